// Round 1
// baseline (134.899 us; speedup 1.0000x reference)
//
#include <hip/hip_runtime.h>
#include <hip/hip_bf16.h>

// Problem: RegionalCosineSimilarityLoss
// B=8, T=2048, C=128; mapping sorted per batch, values in [0,64).
// mask(t,s) = (s>t) & (m_s - m_t <= 3) & (m_t != 0)   [sortedness folds the rest]
// loss = sum_mask (dot(xn_t, xn_s) - [m_s==m_t])^2 / (count + 1e-6)

#define TT 2048
#define CC 128

// ---------------- Kernel 1: row-normalize x -> xn ----------------
// 4 waves/block, one wave per row, lane holds float2 (c = 2*lane, 2*lane+1)
__global__ void __launch_bounds__(256) k_normalize(const float* __restrict__ x,
                                                   float* __restrict__ xn) {
    const int wave = threadIdx.x >> 6;
    const int lane = threadIdx.x & 63;
    const int row  = blockIdx.x * 4 + wave;
    const float2* xr = (const float2*)(x + (size_t)row * CC);
    float2 v = xr[lane];
    float ss = v.x * v.x + v.y * v.y;
    #pragma unroll
    for (int off = 32; off; off >>= 1) ss += __shfl_xor(ss, off);
    const float rn = 1.0f / fmaxf(sqrtf(ss), 1e-8f);
    float2 o; o.x = v.x * rn; o.y = v.y * rn;
    ((float2*)(xn + (size_t)row * CC))[lane] = o;
}

// ---------------- Kernel 2: banded loss partials ----------------
// 4 waves/block, one wave per row t. Stage xn[t] in LDS, lanes split the band.
__global__ void __launch_bounds__(256) k_band(const float* __restrict__ xn,
                                              const int* __restrict__ map,
                                              float* __restrict__ psum,
                                              int* __restrict__ pcnt) {
    __shared__ float xt[4][CC];
    __shared__ float wsum[4];
    __shared__ int   wcnt[4];

    const int wave = threadIdx.x >> 6;
    const int lane = threadIdx.x & 63;
    const int row  = blockIdx.x * 4 + wave;   // absolute row index in [0, B*T)
    const int b    = row >> 11;               // / 2048
    const int t    = row & (TT - 1);

    // stage xn[row] into LDS (this wave's slice)
    float2 v = ((const float2*)(xn + (size_t)row * CC))[lane];
    xt[wave][2 * lane]     = v.x;
    xt[wave][2 * lane + 1] = v.y;
    __syncthreads();

    const int m_t = map[row];
    float acc = 0.0f;
    int   cnt = 0;

    if (m_t != 0) {
        const int* mb = map + b * TT;
        // binary search: first index in (t, T] with mb[i] > m_t+3
        const int key = m_t + 3;
        int lo = t + 1, hi = TT;
        while (lo < hi) {
            int mid = (lo + hi) >> 1;
            if (mb[mid] <= key) lo = mid + 1; else hi = mid;
        }
        const int e = lo - 1;     // last index with mb[e] <= key; e >= t
        cnt = e - t;              // masked count for this row

        const float4* xtv = (const float4*)xt[wave];
        for (int s = t + 1 + lane; s <= e; s += 64) {
            const float4* xs = (const float4*)(xn + ((size_t)b * TT + s) * CC);
            float dot = 0.0f;
            #pragma unroll
            for (int c4 = 0; c4 < CC / 4; ++c4) {
                float4 a  = xtv[c4];
                float4 bb = xs[c4];
                dot += a.x * bb.x + a.y * bb.y + a.z * bb.z + a.w * bb.w;
            }
            const float tgt = (mb[s] == m_t) ? 1.0f : 0.0f;
            const float d = dot - tgt;
            acc += d * d;
        }
    }

    // wave reduce
    #pragma unroll
    for (int off = 32; off; off >>= 1) acc += __shfl_xor(acc, off);

    if (lane == 0) { wsum[wave] = acc; wcnt[wave] = cnt; }
    __syncthreads();
    if (threadIdx.x == 0) {
        psum[blockIdx.x] = wsum[0] + wsum[1] + wsum[2] + wsum[3];
        pcnt[blockIdx.x] = wcnt[0] + wcnt[1] + wcnt[2] + wcnt[3];
    }
}

// ---------------- Kernel 3: final reduce ----------------
__global__ void __launch_bounds__(256) k_final(const float* __restrict__ psum,
                                               const int* __restrict__ pcnt,
                                               float* __restrict__ out, int n) {
    __shared__ double ssum[256];
    __shared__ long long scnt[256];
    double s = 0.0; long long c = 0;
    for (int i = threadIdx.x; i < n; i += 256) { s += (double)psum[i]; c += (long long)pcnt[i]; }
    ssum[threadIdx.x] = s; scnt[threadIdx.x] = c;
    __syncthreads();
    #pragma unroll
    for (int off = 128; off; off >>= 1) {
        if (threadIdx.x < off) {
            ssum[threadIdx.x] += ssum[threadIdx.x + off];
            scnt[threadIdx.x] += scnt[threadIdx.x + off];
        }
        __syncthreads();
    }
    if (threadIdx.x == 0) out[0] = (float)(ssum[0] / ((double)scnt[0] + 1e-6));
}

extern "C" void kernel_launch(void* const* d_in, const int* in_sizes, int n_in,
                              void* d_out, int out_size, void* d_ws, size_t ws_size,
                              hipStream_t stream) {
    (void)n_in; (void)out_size; (void)ws_size;
    const float* x   = (const float*)d_in[0];
    const int*   map = (const int*)d_in[1];
    float* out = (float*)d_out;

    const int n_rows = in_sizes[1];          // B*T = 16384
    const int n_blk  = n_rows / 4;           // 4096

    float* xn   = (float*)d_ws;                                   // B*T*C floats = 8 MiB
    char*  p    = (char*)d_ws + (size_t)in_sizes[0] * sizeof(float);
    float* psum = (float*)p;                                      // n_blk floats
    int*   pcnt = (int*)(p + (size_t)n_blk * sizeof(float));      // n_blk ints

    k_normalize<<<n_blk, 256, 0, stream>>>(x, xn);
    k_band<<<n_blk, 256, 0, stream>>>(xn, map, psum, pcnt);
    k_final<<<1, 256, 0, stream>>>(psum, pcnt, out, n_blk);
}

// Round 2
// 56.535 us; speedup vs baseline: 2.3861x; 2.3861x over previous
//
#include <hip/hip_runtime.h>
#include <hip/hip_bf16.h>

// RegionalCosineSimilarityLoss — B=8, T=2048, C=128; mapping sorted, values in [0,64).
// mask(t,s) = (s>t) & (m_s <= m_t+3) & (m_t != 0)  [sortedness folds neighbor+padding]
// Sorted mapping => per t-tile the masked s-set is a contiguous range [t0+1, e_max]:
// compute it DENSELY as 64x64 dot-tiles (GEMM-style, fp32 VALU), mask in epilogue.

#define TT 2048
#define CC 128
#define TM 64
#define PAD 132   // +4 floats: keeps 16B alignment for float4 LDS reads, 2-way conflicts only

// ---------------- Kernel 1: row-normalize x -> xn ----------------
__global__ void __launch_bounds__(256) k_normalize(const float* __restrict__ x,
                                                   float* __restrict__ xn) {
    const int wave = threadIdx.x >> 6;
    const int lane = threadIdx.x & 63;
    const int row  = blockIdx.x * 4 + wave;
    float2 v = ((const float2*)(x + (size_t)row * CC))[lane];
    float ss = v.x * v.x + v.y * v.y;
    #pragma unroll
    for (int off = 32; off; off >>= 1) ss += __shfl_xor(ss, off);
    const float rn = 1.0f / fmaxf(sqrtf(ss), 1e-8f);
    float2 o; o.x = v.x * rn; o.y = v.y * rn;
    ((float2*)(xn + (size_t)row * CC))[lane] = o;
}

// ---------------- Kernel 2: dense banded tile loss ----------------
// One block per 64-row t-tile. s-chunks of 64 up to e_max. 4x4 register tile/thread.
__global__ void __launch_bounds__(256) k_tile(const float* __restrict__ xn,
                                              const int* __restrict__ map,
                                              float* __restrict__ psum,
                                              int* __restrict__ pcnt) {
    __shared__ float As[TM][PAD];
    __shared__ float Bs[TM][PAD];
    __shared__ int mt[TM], et[TM], ms[TM];
    __shared__ int s_emax;
    __shared__ float wsum[4];
    __shared__ int   wcnt[4];

    const int tid = threadIdx.x;
    const int b   = blockIdx.x >> 5;            // 32 tiles per batch (2048/64)
    const int t0  = (blockIdx.x & 31) * TM;
    const int* mb = map + b * TT;
    const float* xb = xn + (size_t)b * TT * CC;

    if (tid == 0) s_emax = t0;

    // stage A tile (64x128), fully coalesced float4
    #pragma unroll
    for (int q = 0; q < 8; ++q) {
        int f = tid + q * 256;                  // 0..2047 float4s
        int row = f >> 5, k4 = (f & 31) << 2;
        *(float4*)&As[row][k4] = *(const float4*)(xb + (size_t)(t0 + row) * CC + k4);
    }
    // per-row mapping value + band end via binary search
    if (tid < TM) {
        int t = t0 + tid;
        int m = mb[t];
        int e = t;                              // empty band if m==0
        if (m != 0) {
            int key = m + 3, lo = t + 1, hi = TT;
            while (lo < hi) { int mid = (lo + hi) >> 1; if (mb[mid] <= key) lo = mid + 1; else hi = mid; }
            e = lo - 1;
            atomicMax(&s_emax, e);
        }
        mt[tid] = m; et[tid] = e;
    }
    __syncthreads();

    const int tr = tid & 15, tc = tid >> 4;     // 16x16 threads -> 64x64 outputs
    int mt_l[4], et_l[4];
    #pragma unroll
    for (int i = 0; i < 4; ++i) { mt_l[i] = mt[tr * 4 + i]; et_l[i] = et[tr * 4 + i]; }
    const int emax = s_emax;

    float lsum = 0.0f;
    int   lcnt = 0;

    for (int s_base = t0; s_base <= emax; s_base += TM) {
        // stage B chunk (64x128) + its mapping values
        #pragma unroll
        for (int q = 0; q < 8; ++q) {
            int f = tid + q * 256;
            int row = f >> 5, k4 = (f & 31) << 2;
            *(float4*)&Bs[row][k4] = *(const float4*)(xb + (size_t)(s_base + row) * CC + k4);
        }
        if (tid < TM) ms[tid] = mb[s_base + tid];
        __syncthreads();

        float acc[4][4] = {};
        #pragma unroll 4
        for (int k4 = 0; k4 < CC; k4 += 4) {
            float4 a4[4], b4[4];
            #pragma unroll
            for (int i = 0; i < 4; ++i) a4[i] = *(const float4*)&As[tr * 4 + i][k4];
            #pragma unroll
            for (int j = 0; j < 4; ++j) b4[j] = *(const float4*)&Bs[tc * 4 + j][k4];
            #pragma unroll
            for (int i = 0; i < 4; ++i)
                #pragma unroll
                for (int j = 0; j < 4; ++j)
                    acc[i][j] += a4[i].x * b4[j].x + a4[i].y * b4[j].y
                               + a4[i].z * b4[j].z + a4[i].w * b4[j].w;
        }

        // masked epilogue
        #pragma unroll
        for (int j = 0; j < 4; ++j) {
            int s   = s_base + tc * 4 + j;
            int msj = ms[tc * 4 + j];
            #pragma unroll
            for (int i = 0; i < 4; ++i) {
                int t = t0 + tr * 4 + i;
                if ((s > t) & (s <= et_l[i]) & (mt_l[i] != 0)) {
                    float d = acc[i][j] - (msj == mt_l[i] ? 1.0f : 0.0f);
                    lsum += d * d;
                    lcnt += 1;
                }
            }
        }
        __syncthreads();   // protect Bs/ms before next chunk's staging
    }

    // block reduce (sum + count)
    #pragma unroll
    for (int off = 32; off; off >>= 1) {
        lsum += __shfl_xor(lsum, off);
        lcnt += __shfl_xor(lcnt, off);
    }
    const int wave = tid >> 6, lane = tid & 63;
    if (lane == 0) { wsum[wave] = lsum; wcnt[wave] = lcnt; }
    __syncthreads();
    if (tid == 0) {
        psum[blockIdx.x] = wsum[0] + wsum[1] + wsum[2] + wsum[3];
        pcnt[blockIdx.x] = wcnt[0] + wcnt[1] + wcnt[2] + wcnt[3];
    }
}

// ---------------- Kernel 3: final reduce ----------------
__global__ void __launch_bounds__(256) k_final(const float* __restrict__ psum,
                                               const int* __restrict__ pcnt,
                                               float* __restrict__ out, int n) {
    __shared__ double ssum[256];
    __shared__ long long scnt[256];
    double s = 0.0; long long c = 0;
    for (int i = threadIdx.x; i < n; i += 256) { s += (double)psum[i]; c += (long long)pcnt[i]; }
    ssum[threadIdx.x] = s; scnt[threadIdx.x] = c;
    __syncthreads();
    #pragma unroll
    for (int off = 128; off; off >>= 1) {
        if (threadIdx.x < off) {
            ssum[threadIdx.x] += ssum[threadIdx.x + off];
            scnt[threadIdx.x] += scnt[threadIdx.x + off];
        }
        __syncthreads();
    }
    if (threadIdx.x == 0) out[0] = (float)(ssum[0] / ((double)scnt[0] + 1e-6));
}

extern "C" void kernel_launch(void* const* d_in, const int* in_sizes, int n_in,
                              void* d_out, int out_size, void* d_ws, size_t ws_size,
                              hipStream_t stream) {
    (void)n_in; (void)out_size; (void)ws_size;
    const float* x   = (const float*)d_in[0];
    const int*   map = (const int*)d_in[1];
    float* out = (float*)d_out;

    const int n_rows  = in_sizes[1];            // B*T = 16384
    const int n_norm  = n_rows / 4;             // 4096 blocks, 4 rows each
    const int n_tiles = n_rows / TM;            // 256 blocks

    float* xn   = (float*)d_ws;                                    // 8 MiB
    char*  p    = (char*)d_ws + (size_t)in_sizes[0] * sizeof(float);
    float* psum = (float*)p;                                       // n_tiles floats
    int*   pcnt = (int*)(p + (size_t)n_tiles * sizeof(float));     // n_tiles ints

    k_normalize<<<n_norm, 256, 0, stream>>>(x, xn);
    k_tile<<<n_tiles, 256, 0, stream>>>(xn, map, psum, pcnt);
    k_final<<<1, 256, 0, stream>>>(psum, pcnt, out, n_tiles);
}

// Round 3
// 46.792 us; speedup vs baseline: 2.8829x; 1.2082x over previous
//
#include <hip/hip_runtime.h>
#include <hip/hip_bf16.h>

// RegionalCosineSimilarityLoss — B=8, T=2048, C=128; mapping sorted per batch, [0,64).
// mask(t,s) = (s>t) & (m_s <= m_t+3) & (m_t != 0)  [sortedness folds neighbor+padding]
// Dense 64x64 dot-tiles over the contiguous masked band; scale by 1/norms in epilogue.

#define TT 2048
#define CC 128
#define TM 64
#define SLOTS 8   // grid.y chunk slots; while-stride covers any band length

// ---------------- Kernel 1: row norms -> rn = 1/max(||x||, eps) ----------------
__global__ void __launch_bounds__(256) k_norms(const float* __restrict__ x,
                                               float* __restrict__ rn) {
    const int wave = threadIdx.x >> 6;
    const int lane = threadIdx.x & 63;
    const int row  = blockIdx.x * 4 + wave;
    float2 v = ((const float2*)(x + (size_t)row * CC))[lane];
    float ss = v.x * v.x + v.y * v.y;
    #pragma unroll
    for (int off = 32; off; off >>= 1) ss += __shfl_xor(ss, off);
    if (lane == 0) rn[row] = 1.0f / fmaxf(sqrtf(ss), 1e-8f);
}

// ---------------- Kernel 2: one (t-tile, s-chunk) per block ----------------
// 16x16 threads x 4x4 register tile = 64x64 dots. XOR-swizzled LDS, raw-x dots.
__global__ void __launch_bounds__(256) k_tile(const float* __restrict__ x,
                                              const float* __restrict__ rn,
                                              const int* __restrict__ map,
                                              float* __restrict__ psum,
                                              int* __restrict__ pcnt) {
    __shared__ float As[TM][CC];     // swizzled: float4-col c4 stored at c4 ^ ((row>>2)&7)
    __shared__ float Bs[TM][CC];
    __shared__ float rnA[TM], rnB[TM];
    __shared__ int mt[TM], et[TM], ms[TM];
    __shared__ int s_emax;
    __shared__ float wsum[4];

    const int tile = blockIdx.x;              // 0..255
    const int slot = blockIdx.y;              // 0..SLOTS-1
    const int tid  = threadIdx.x;
    const int b    = tile >> 5;               // 32 tiles per batch
    const int t0   = (tile & 31) * TM;
    const int* mb  = map + b * TT;
    const float* xb = x + (size_t)b * TT * CC;

    if (tid == 0) s_emax = t0;
    __syncthreads();

    // per-row mapping value, band end (binary search), tile-max band end
    if (tid < TM) {
        const int t = t0 + tid;
        const int m = mb[t];
        int e = t;                            // empty band when m==0
        if (m != 0) {
            const int key = m + 3;
            int lo = t + 1, hi = TT;
            while (lo < hi) { int mid = (lo + hi) >> 1; if (mb[mid] <= key) lo = mid + 1; else hi = mid; }
            e = lo - 1;
            atomicMax(&s_emax, e);
        }
        mt[tid] = m; et[tid] = e;
        rnA[tid] = rn[b * TT + t];
    }
    __syncthreads();
    const int emax = s_emax;

    // count (slot 0 only): sum of band lengths over this tile's rows
    if (slot == 0 && tid < TM) {
        int c = et[tid] - (t0 + tid);
        #pragma unroll
        for (int off = 32; off; off >>= 1) c += __shfl_xor(c, off);
        if (tid == 0) pcnt[tile] = c;
    }

    int s_base = t0 + slot * TM;
    if (s_base > emax) {                      // inactive slot: record zero, leave
        if (tid == 0) psum[tile * SLOTS + slot] = 0.0f;
        return;
    }

    // stage A tile (64x128 raw x), swizzled, fully coalesced
    #pragma unroll
    for (int q = 0; q < 8; ++q) {
        const int f = tid + q * 256;
        const int row = f >> 5, c4 = f & 31;
        const int c4s = c4 ^ ((row >> 2) & 7);
        *(float4*)&As[row][c4s << 2] = *(const float4*)(xb + (size_t)(t0 + row) * CC + (c4 << 2));
    }

    const int tr = tid & 15, tc = tid >> 4;
    const int swa = tr & 7, swb = tc & 7;
    int mt_l[4], et_l[4]; float ra[4];
    #pragma unroll
    for (int i = 0; i < 4; ++i) { mt_l[i] = mt[tr * 4 + i]; et_l[i] = et[tr * 4 + i]; ra[i] = rnA[tr * 4 + i]; }

    float lsum = 0.0f;

    for (; s_base <= emax; s_base += SLOTS * TM) {
        // stage B chunk + its mapping values + norms
        #pragma unroll
        for (int q = 0; q < 8; ++q) {
            const int f = tid + q * 256;
            const int row = f >> 5, c4 = f & 31;
            const int c4s = c4 ^ ((row >> 2) & 7);
            *(float4*)&Bs[row][c4s << 2] = *(const float4*)(xb + (size_t)(s_base + row) * CC + (c4 << 2));
        }
        if (tid < TM) { ms[tid] = mb[s_base + tid]; rnB[tid] = rn[b * TT + s_base + tid]; }
        __syncthreads();

        float acc[4][4] = {};
        #pragma unroll 4
        for (int c4 = 0; c4 < CC / 4; ++c4) {
            float4 a4[4], b4[4];
            const int ca = (c4 ^ swa) << 2;
            const int cb = (c4 ^ swb) << 2;
            #pragma unroll
            for (int i = 0; i < 4; ++i) a4[i] = *(const float4*)&As[tr * 4 + i][ca];
            #pragma unroll
            for (int j = 0; j < 4; ++j) b4[j] = *(const float4*)&Bs[tc * 4 + j][cb];
            #pragma unroll
            for (int i = 0; i < 4; ++i)
                #pragma unroll
                for (int j = 0; j < 4; ++j)
                    acc[i][j] += a4[i].x * b4[j].x + a4[i].y * b4[j].y
                               + a4[i].z * b4[j].z + a4[i].w * b4[j].w;
        }

        // masked epilogue: cos = dot * rn_t * rn_s
        #pragma unroll
        for (int j = 0; j < 4; ++j) {
            const int s   = s_base + tc * 4 + j;
            const int msj = ms[tc * 4 + j];
            const float rb = rnB[tc * 4 + j];
            #pragma unroll
            for (int i = 0; i < 4; ++i) {
                const int t = t0 + tr * 4 + i;
                if ((s > t) & (s <= et_l[i]) & (mt_l[i] != 0)) {
                    const float d = acc[i][j] * ra[i] * rb - (msj == mt_l[i] ? 1.0f : 0.0f);
                    lsum += d * d;
                }
            }
        }
        __syncthreads();   // protect Bs/ms/rnB before next chunk's staging
    }

    // block reduce
    #pragma unroll
    for (int off = 32; off; off >>= 1) lsum += __shfl_xor(lsum, off);
    const int wave = tid >> 6, lane = tid & 63;
    if (lane == 0) wsum[wave] = lsum;
    __syncthreads();
    if (tid == 0) psum[tile * SLOTS + slot] = wsum[0] + wsum[1] + wsum[2] + wsum[3];
}

// ---------------- Kernel 3: final reduce ----------------
__global__ void __launch_bounds__(256) k_final(const float* __restrict__ psum,
                                               const int* __restrict__ pcnt,
                                               float* __restrict__ out,
                                               int n_sum, int n_cnt) {
    __shared__ double ssum[256];
    __shared__ long long scnt[256];
    double s = 0.0; long long c = 0;
    for (int i = threadIdx.x; i < n_sum; i += 256) s += (double)psum[i];
    for (int i = threadIdx.x; i < n_cnt; i += 256) c += (long long)pcnt[i];
    ssum[threadIdx.x] = s; scnt[threadIdx.x] = c;
    __syncthreads();
    #pragma unroll
    for (int off = 128; off; off >>= 1) {
        if (threadIdx.x < off) {
            ssum[threadIdx.x] += ssum[threadIdx.x + off];
            scnt[threadIdx.x] += scnt[threadIdx.x + off];
        }
        __syncthreads();
    }
    if (threadIdx.x == 0) out[0] = (float)(ssum[0] / ((double)scnt[0] + 1e-6));
}

extern "C" void kernel_launch(void* const* d_in, const int* in_sizes, int n_in,
                              void* d_out, int out_size, void* d_ws, size_t ws_size,
                              hipStream_t stream) {
    (void)n_in; (void)out_size; (void)ws_size;
    const float* x   = (const float*)d_in[0];
    const int*   map = (const int*)d_in[1];
    float* out = (float*)d_out;

    const int n_rows  = in_sizes[1];            // B*T = 16384
    const int n_norm  = n_rows / 4;             // 4096
    const int n_tiles = n_rows / TM;            // 256

    float* rnw  = (float*)d_ws;                                     // n_rows floats
    float* psum = (float*)((char*)d_ws + (size_t)n_rows * 4);       // n_tiles*SLOTS floats
    int*   pcnt = (int*)((char*)psum + (size_t)n_tiles * SLOTS * 4);// n_tiles ints

    k_norms<<<n_norm, 256, 0, stream>>>(x, rnw);
    k_tile<<<dim3(n_tiles, SLOTS), 256, 0, stream>>>(x, rnw, map, psum, pcnt);
    k_final<<<1, 256, 0, stream>>>(psum, pcnt, out, n_tiles * SLOTS, n_tiles);
}

// Round 4
// 38.627 us; speedup vs baseline: 3.4924x; 1.2114x over previous
//
#include <hip/hip_runtime.h>

// RegionalCosineSimilarityLoss — B=8, T=2048, C=128; mapping sorted per batch, [0,64).
// mask(t,s) = (s>t) & (m_s <= m_t+3) & (m_t != 0)   [sortedness folds neighbor+padding]
// R4: bf16 MFMA dense band tiles; et[] precomputed; swizzled global_load_lds staging.

#define TT 2048
#define CC 128
#define TM 64
#define SLOTS 4

typedef unsigned short ushort_t;
typedef __attribute__((ext_vector_type(8))) short v8s;   // 8 bf16 (4 VGPRs)
typedef __attribute__((ext_vector_type(4))) float v4f;   // MFMA accumulator

__device__ __forceinline__ ushort_t f2bf(float f) {      // RNE f32->bf16 (finite data)
    unsigned u = __float_as_uint(f);
    return (ushort_t)((u + 0x7FFFu + ((u >> 16) & 1u)) >> 16);
}

// ---------------- Kernel 1: normalize -> bf16, and band-end per row ----------------
// 4 waves/block, one wave per row.
__global__ void __launch_bounds__(256) k_prep(const float* __restrict__ x,
                                              const int* __restrict__ map,
                                              ushort_t* __restrict__ xnb,
                                              int* __restrict__ et) {
    const int wave = threadIdx.x >> 6;
    const int lane = threadIdx.x & 63;
    const int row  = blockIdx.x * 4 + wave;
    float2 v = ((const float2*)(x + (size_t)row * CC))[lane];
    float ss = v.x * v.x + v.y * v.y;
    #pragma unroll
    for (int off = 32; off; off >>= 1) ss += __shfl_xor(ss, off);
    const float rn = 1.0f / fmaxf(sqrtf(ss), 1e-8f);
    const unsigned lo = f2bf(v.x * rn), hi = f2bf(v.y * rn);
    ((unsigned*)(xnb + (size_t)row * CC))[lane] = lo | (hi << 16);

    if (lane == 0) {  // band end: last s with m_s <= m_t+3 (==t when m_t==0)
        const int b = row >> 11, t = row & (TT - 1);
        const int* mb = map + b * TT;
        const int m = mb[t];
        int e = t;
        if (m != 0) {
            const int key = m + 3;
            int l = t + 1, h = TT;
            while (l < h) { int mid = (l + h) >> 1; if (mb[mid] <= key) l = mid + 1; else h = mid; }
            e = l - 1;
        }
        et[row] = e;
    }
}

// ---------------- Kernel 2: MFMA band tiles ----------------
// Block 256 = 4 waves; wave (wr,wc) owns a 32x32 quadrant of the 64x64 tile.
// LDS: bf16 [64 rows][16 x 16B-chunks], chunk-slot swizzled sl^=(row&7).
__global__ void __launch_bounds__(256) k_tile(const ushort_t* __restrict__ xnb,
                                              const int* __restrict__ map,
                                              const int* __restrict__ et,
                                              float* __restrict__ psum) {
    __shared__ __align__(16) ushort_t As[TM * CC];   // 16 KB
    __shared__ __align__(16) ushort_t Bs[TM * CC];   // 16 KB
    __shared__ int mt_s[TM], et_s[TM], ms_s[TM];
    __shared__ float wsum[4];

    const int tile = blockIdx.x;              // 0..255
    const int slot = blockIdx.y;              // 0..SLOTS-1
    const int tid  = threadIdx.x;
    const int lane = tid & 63;
    const int wave = tid >> 6;
    const int b    = tile >> 5;
    const int t0   = (tile & 31) * TM;
    const int* mb  = map + b * TT;
    const ushort_t* xb = xnb + (size_t)(b * TT) * CC;

    if (tid < TM) {
        mt_s[tid] = mb[t0 + tid];
        et_s[tid] = et[b * TT + t0 + tid];
    }
    __syncthreads();

    int e = et_s[lane];
    #pragma unroll
    for (int off = 32; off; off >>= 1) e = max(e, __shfl_xor(e, off));
    const int emax = e;

    int s_base = t0 + slot * TM;
    if (s_base > emax) {                      // inactive slot
        if (tid == 0) psum[tile * SLOTS + slot] = 0.0f;
        return;
    }

    // ---- stage A (once): linear LDS dst, pre-swizzled global src ----
    #pragma unroll
    for (int i = 0; i < 4; ++i) {
        const int pbase = wave * 256 + i * 64;
        const int p = pbase + lane;                   // LDS chunk = base + lane
        const int row = p >> 4;
        const int sl  = (p & 15) ^ (row & 7);         // source slot carries the swizzle
        __builtin_amdgcn_global_load_lds(
            (const __attribute__((address_space(1))) void*)(xb + (size_t)(t0 + row) * CC + sl * 8),
            (__attribute__((address_space(3))) void*)(&As[pbase * 8]), 16, 0, 0);
    }

    const int wr = wave >> 1, wc = wave & 1;
    const int r16 = lane & 15, kgrp = lane >> 4;
    const int rowA0 = wr * 32 + r16, rowA1 = rowA0 + 16;
    const int rowB0 = wc * 32 + r16, rowB1 = rowB0 + 16;

    float lsum = 0.0f;

    for (; s_base <= emax; s_base += SLOTS * TM) {
        // ---- stage B chunk + its map values ----
        #pragma unroll
        for (int i = 0; i < 4; ++i) {
            const int pbase = wave * 256 + i * 64;
            const int p = pbase + lane;
            const int row = p >> 4;
            const int sl  = (p & 15) ^ (row & 7);
            __builtin_amdgcn_global_load_lds(
                (const __attribute__((address_space(1))) void*)(xb + (size_t)(s_base + row) * CC + sl * 8),
                (__attribute__((address_space(3))) void*)(&Bs[pbase * 8]), 16, 0, 0);
        }
        if (tid < TM) ms_s[tid] = mb[s_base + tid];
        __syncthreads();   // drains global_load_lds (compiler emits vmcnt(0))

        v4f acc00 = {0,0,0,0}, acc01 = {0,0,0,0}, acc10 = {0,0,0,0}, acc11 = {0,0,0,0};
        #pragma unroll
        for (int kk = 0; kk < 4; ++kk) {
            const int sl = kk * 4 + kgrp;
            v8s a0 = *(const v8s*)&As[(rowA0 * 16 + (sl ^ (rowA0 & 7))) * 8];
            v8s a1 = *(const v8s*)&As[(rowA1 * 16 + (sl ^ (rowA1 & 7))) * 8];
            v8s b0 = *(const v8s*)&Bs[(rowB0 * 16 + (sl ^ (rowB0 & 7))) * 8];
            v8s b1 = *(const v8s*)&Bs[(rowB1 * 16 + (sl ^ (rowB1 & 7))) * 8];
            acc00 = __builtin_amdgcn_mfma_f32_16x16x32_bf16(a0, b0, acc00, 0, 0, 0);
            acc01 = __builtin_amdgcn_mfma_f32_16x16x32_bf16(a0, b1, acc01, 0, 0, 0);
            acc10 = __builtin_amdgcn_mfma_f32_16x16x32_bf16(a1, b0, acc10, 0, 0, 0);
            acc11 = __builtin_amdgcn_mfma_f32_16x16x32_bf16(a1, b1, acc11, 0, 0, 0);
        }

        // ---- masked epilogue: C row=(lane>>4)*4+reg (t), col=lane&15 (s) ----
        #pragma unroll
        for (int fi = 0; fi < 2; ++fi) {
            #pragma unroll
            for (int fj = 0; fj < 2; ++fj) {
                const v4f a = fi == 0 ? (fj == 0 ? acc00 : acc01) : (fj == 0 ? acc10 : acc11);
                const int s_loc = wc * 32 + fj * 16 + r16;
                const int s     = s_base + s_loc;
                const int m_s   = ms_s[s_loc];
                #pragma unroll
                for (int r = 0; r < 4; ++r) {
                    const int t_loc = wr * 32 + fi * 16 + kgrp * 4 + r;
                    const int t     = t0 + t_loc;
                    const int m_t   = mt_s[t_loc];
                    if ((m_t != 0) & (s > t) & (s <= et_s[t_loc])) {
                        const float d = a[r] - (m_s == m_t ? 1.0f : 0.0f);
                        lsum += d * d;
                    }
                }
            }
        }
        __syncthreads();   // protect Bs/ms before restage (rare multi-pass)
    }

    #pragma unroll
    for (int off = 32; off; off >>= 1) lsum += __shfl_xor(lsum, off);
    if (lane == 0) wsum[wave] = lsum;
    __syncthreads();
    if (tid == 0) psum[tile * SLOTS + slot] = wsum[0] + wsum[1] + wsum[2] + wsum[3];
}

// ---------------- Kernel 3: final reduce (count from et, no atomics) ----------------
__global__ void __launch_bounds__(256) k_final(const float* __restrict__ psum,
                                               const int* __restrict__ et,
                                               float* __restrict__ out,
                                               int n_sum, int n_rows) {
    __shared__ double ssum[256];
    __shared__ long long scnt[256];
    double s = 0.0; long long c = 0;
    for (int i = threadIdx.x; i < n_sum; i += 256) s += (double)psum[i];
    for (int i = threadIdx.x; i < n_rows; i += 256) c += (long long)(et[i] - (i & (TT - 1)));
    ssum[threadIdx.x] = s; scnt[threadIdx.x] = c;
    __syncthreads();
    #pragma unroll
    for (int off = 128; off; off >>= 1) {
        if (threadIdx.x < off) {
            ssum[threadIdx.x] += ssum[threadIdx.x + off];
            scnt[threadIdx.x] += scnt[threadIdx.x + off];
        }
        __syncthreads();
    }
    if (threadIdx.x == 0) out[0] = (float)(ssum[0] / ((double)scnt[0] + 1e-6));
}

extern "C" void kernel_launch(void* const* d_in, const int* in_sizes, int n_in,
                              void* d_out, int out_size, void* d_ws, size_t ws_size,
                              hipStream_t stream) {
    (void)n_in; (void)out_size; (void)ws_size;
    const float* x   = (const float*)d_in[0];
    const int*   map = (const int*)d_in[1];
    float* out = (float*)d_out;

    const int n_rows  = in_sizes[1];            // B*T = 16384
    const int n_tiles = n_rows / TM;            // 256

    ushort_t* xnb = (ushort_t*)d_ws;                                  // 4 MiB
    int*      etw = (int*)((char*)d_ws + (size_t)n_rows * CC * 2);    // 64 KiB
    float*    ps  = (float*)((char*)etw + (size_t)n_rows * 4);        // n_tiles*SLOTS

    k_prep <<<n_rows / 4, 256, 0, stream>>>(x, map, xnb, etw);
    k_tile <<<dim3(n_tiles, SLOTS), 256, 0, stream>>>(xnb, map, etw, ps);
    k_final<<<1, 256, 0, stream>>>(ps, etw, out, n_tiles * SLOTS, n_rows);
}

// Round 5
// 19.841 us; speedup vs baseline: 6.7989x; 1.9468x over previous
//
#include <hip/hip_runtime.h>

// RegionalCosineSimilarityLoss — B=8, T=2048, C=128; mapping sorted per batch, [0,64).
// mask(t,s) = (s>t) & (m_s <= m_t+3) & (m_t != 0)   [sortedness folds neighbor+padding]
// R5: k_prep = pure normalize->bf16 (no serial tail); searches parallel in k_tile;
//     k_final back to tiny psum/pcnt reads. MFMA core identical to R4 (validated).

#define TT 2048
#define CC 128
#define TM 64
#define SLOTS 4

typedef unsigned short ushort_t;
typedef __attribute__((ext_vector_type(8))) short v8s;   // 8 bf16 (4 VGPRs)
typedef __attribute__((ext_vector_type(4))) float v4f;   // MFMA accumulator

__device__ __forceinline__ ushort_t f2bf(float f) {      // RNE f32->bf16 (finite data)
    unsigned u = __float_as_uint(f);
    return (ushort_t)((u + 0x7FFFu + ((u >> 16) & 1u)) >> 16);
}

// ---------------- Kernel 1: normalize -> bf16 (pure, no tail) ----------------
__global__ void __launch_bounds__(256) k_prep(const float* __restrict__ x,
                                              ushort_t* __restrict__ xnb) {
    const int wave = threadIdx.x >> 6;
    const int lane = threadIdx.x & 63;
    const int row  = blockIdx.x * 4 + wave;
    float2 v = ((const float2*)(x + (size_t)row * CC))[lane];
    float ss = v.x * v.x + v.y * v.y;
    #pragma unroll
    for (int off = 32; off; off >>= 1) ss += __shfl_xor(ss, off);
    const float rn = 1.0f / fmaxf(sqrtf(ss), 1e-8f);
    const unsigned lo = f2bf(v.x * rn), hi = f2bf(v.y * rn);
    ((unsigned*)(xnb + (size_t)row * CC))[lane] = lo | (hi << 16);
}

// ---------------- Kernel 2: MFMA band tiles ----------------
// 4 waves; wave (wr,wc) owns a 32x32 quadrant of the 64x64 tile.
// LDS bf16 [64 rows][16 chunks of 16B], chunk-slot swizzle sl^=(row&7),
// linear LDS dst + pre-swizzled global src (global_load_lds).
__global__ void __launch_bounds__(256) k_tile(const ushort_t* __restrict__ xnb,
                                              const int* __restrict__ map,
                                              float* __restrict__ psum,
                                              int* __restrict__ pcnt) {
    __shared__ __align__(16) ushort_t As[TM * CC];   // 16 KB
    __shared__ __align__(16) ushort_t Bs[TM * CC];   // 16 KB
    __shared__ int mt_s[TM], et_s[TM], ms_s[TM];
    __shared__ float wsum[4];

    const int tile = blockIdx.x;              // 0..255
    const int slot = blockIdx.y;              // 0..SLOTS-1
    const int tid  = threadIdx.x;
    const int lane = tid & 63;
    const int wave = tid >> 6;
    const int b    = tile >> 5;
    const int t0   = (tile & 31) * TM;
    const int* mb  = map + b * TT;
    const ushort_t* xb = xnb + (size_t)(b * TT) * CC;

    // 64 parallel binary searches (threads 0..63), ~11 L1-hot loads each
    if (tid < TM) {
        const int t = t0 + tid;
        const int m = mb[t];
        int e = t;                            // empty band when m==0
        if (m != 0) {
            const int key = m + 3;
            int lo = t + 1, hi = TT;
            while (lo < hi) { int mid = (lo + hi) >> 1; if (mb[mid] <= key) lo = mid + 1; else hi = mid; }
            e = lo - 1;
        }
        mt_s[tid] = m; et_s[tid] = e;
    }
    __syncthreads();

    int e = et_s[lane];
    #pragma unroll
    for (int off = 32; off; off >>= 1) e = max(e, __shfl_xor(e, off));
    const int emax = e;

    // per-tile masked count (slot 0, wave 0): sum over rows of band length
    if (slot == 0 && wave == 0) {
        int c = et_s[lane] - (t0 + lane);
        #pragma unroll
        for (int off = 32; off; off >>= 1) c += __shfl_xor(c, off);
        if (lane == 0) pcnt[tile] = c;
    }

    int s_base = t0 + slot * TM;
    if (s_base > emax) {                      // inactive slot (no async loads issued yet)
        if (tid == 0) psum[tile * SLOTS + slot] = 0.0f;
        return;
    }

    // ---- stage A (once): linear LDS dst, pre-swizzled global src ----
    #pragma unroll
    for (int i = 0; i < 4; ++i) {
        const int pbase = wave * 256 + i * 64;
        const int p = pbase + lane;
        const int row = p >> 4;
        const int sl  = (p & 15) ^ (row & 7);
        __builtin_amdgcn_global_load_lds(
            (const __attribute__((address_space(1))) void*)(xb + (size_t)(t0 + row) * CC + sl * 8),
            (__attribute__((address_space(3))) void*)(&As[pbase * 8]), 16, 0, 0);
    }

    const int wr = wave >> 1, wc = wave & 1;
    const int r16 = lane & 15, kgrp = lane >> 4;
    const int rowA0 = wr * 32 + r16, rowA1 = rowA0 + 16;
    const int rowB0 = wc * 32 + r16, rowB1 = rowB0 + 16;

    float lsum = 0.0f;

    for (; s_base <= emax; s_base += SLOTS * TM) {
        // ---- stage B chunk + its map values ----
        #pragma unroll
        for (int i = 0; i < 4; ++i) {
            const int pbase = wave * 256 + i * 64;
            const int p = pbase + lane;
            const int row = p >> 4;
            const int sl  = (p & 15) ^ (row & 7);
            __builtin_amdgcn_global_load_lds(
                (const __attribute__((address_space(1))) void*)(xb + (size_t)(s_base + row) * CC + sl * 8),
                (__attribute__((address_space(3))) void*)(&Bs[pbase * 8]), 16, 0, 0);
        }
        if (tid < TM) ms_s[tid] = mb[s_base + tid];
        __syncthreads();   // drains global_load_lds (compiler emits vmcnt(0))

        v4f acc00 = {0,0,0,0}, acc01 = {0,0,0,0}, acc10 = {0,0,0,0}, acc11 = {0,0,0,0};
        #pragma unroll
        for (int kk = 0; kk < 4; ++kk) {
            const int sl = kk * 4 + kgrp;
            v8s a0 = *(const v8s*)&As[(rowA0 * 16 + (sl ^ (rowA0 & 7))) * 8];
            v8s a1 = *(const v8s*)&As[(rowA1 * 16 + (sl ^ (rowA1 & 7))) * 8];
            v8s b0 = *(const v8s*)&Bs[(rowB0 * 16 + (sl ^ (rowB0 & 7))) * 8];
            v8s b1 = *(const v8s*)&Bs[(rowB1 * 16 + (sl ^ (rowB1 & 7))) * 8];
            acc00 = __builtin_amdgcn_mfma_f32_16x16x32_bf16(a0, b0, acc00, 0, 0, 0);
            acc01 = __builtin_amdgcn_mfma_f32_16x16x32_bf16(a0, b1, acc01, 0, 0, 0);
            acc10 = __builtin_amdgcn_mfma_f32_16x16x32_bf16(a1, b0, acc10, 0, 0, 0);
            acc11 = __builtin_amdgcn_mfma_f32_16x16x32_bf16(a1, b1, acc11, 0, 0, 0);
        }

        // ---- masked epilogue: C row=(lane>>4)*4+reg (t), col=lane&15 (s) ----
        #pragma unroll
        for (int fi = 0; fi < 2; ++fi) {
            #pragma unroll
            for (int fj = 0; fj < 2; ++fj) {
                const v4f a = fi == 0 ? (fj == 0 ? acc00 : acc01) : (fj == 0 ? acc10 : acc11);
                const int s_loc = wc * 32 + fj * 16 + r16;
                const int s     = s_base + s_loc;
                const int m_s   = ms_s[s_loc];
                #pragma unroll
                for (int r = 0; r < 4; ++r) {
                    const int t_loc = wr * 32 + fi * 16 + kgrp * 4 + r;
                    const int t     = t0 + t_loc;
                    const int m_t   = mt_s[t_loc];
                    if ((m_t != 0) & (s > t) & (s <= et_s[t_loc])) {
                        const float d = a[r] - (m_s == m_t ? 1.0f : 0.0f);
                        lsum += d * d;
                    }
                }
            }
        }
        __syncthreads();   // protect Bs/ms before restage (rare multi-pass)
    }

    #pragma unroll
    for (int off = 32; off; off >>= 1) lsum += __shfl_xor(lsum, off);
    if (lane == 0) wsum[wave] = lsum;
    __syncthreads();
    if (tid == 0) psum[tile * SLOTS + slot] = wsum[0] + wsum[1] + wsum[2] + wsum[3];
}

// ---------------- Kernel 3: final reduce (tiny reads) ----------------
__global__ void __launch_bounds__(256) k_final(const float* __restrict__ psum,
                                               const int* __restrict__ pcnt,
                                               float* __restrict__ out,
                                               int n_sum, int n_cnt) {
    __shared__ double ssum[256];
    __shared__ long long scnt[256];
    double s = 0.0; long long c = 0;
    for (int i = threadIdx.x; i < n_sum; i += 256) s += (double)psum[i];
    for (int i = threadIdx.x; i < n_cnt; i += 256) c += (long long)pcnt[i];
    ssum[threadIdx.x] = s; scnt[threadIdx.x] = c;
    __syncthreads();
    #pragma unroll
    for (int off = 128; off; off >>= 1) {
        if (threadIdx.x < off) {
            ssum[threadIdx.x] += ssum[threadIdx.x + off];
            scnt[threadIdx.x] += scnt[threadIdx.x + off];
        }
        __syncthreads();
    }
    if (threadIdx.x == 0) out[0] = (float)(ssum[0] / ((double)scnt[0] + 1e-6));
}

extern "C" void kernel_launch(void* const* d_in, const int* in_sizes, int n_in,
                              void* d_out, int out_size, void* d_ws, size_t ws_size,
                              hipStream_t stream) {
    (void)n_in; (void)out_size; (void)ws_size;
    const float* x   = (const float*)d_in[0];
    const int*   map = (const int*)d_in[1];
    float* out = (float*)d_out;

    const int n_rows  = in_sizes[1];            // B*T = 16384
    const int n_tiles = n_rows / TM;            // 256

    ushort_t* xnb = (ushort_t*)d_ws;                                  // 4 MiB
    float*    ps  = (float*)((char*)d_ws + (size_t)n_rows * CC * 2);  // n_tiles*SLOTS floats
    int*      pc  = (int*)((char*)ps + (size_t)n_tiles * SLOTS * 4);  // n_tiles ints

    k_prep <<<n_rows / 4, 256, 0, stream>>>(x, xnb);
    k_tile <<<dim3(n_tiles, SLOTS), 256, 0, stream>>>(xnb, map, ps, pc);
    k_final<<<1, 256, 0, stream>>>(ps, pc, out, n_tiles * SLOTS, n_tiles);
}